// Round 3
// baseline (170.142 us; speedup 1.0000x reference)
//
#include <hip/hip_runtime.h>
#include <math.h>

namespace {

constexpr int NB = 64, NT = 16384;
constexpr int NBT = NB * NT;              // 1,048,576 (b,t) pairs, 4 sources each
constexpr int NBLK   = 1024;              // blocks
constexpr int NTHR   = 256;
constexpr int NPASS  = NBT / (NBLK * NTHR);   // 4 pairs per thread
constexpr float VAD_TH  = 2.0f / 3.0f;
constexpr float AE_TH   = 30.0f;
constexpr float D2R     = 0.017453292519943295f;
constexpr float R2D     = 57.29577951308232f;
constexpr float CLIPV   = 0.99999f;

// ws layout: float part[5][NBLK] (20480 B), then unsigned int counter @ 20480.
// metrics: 0=act 1=corr 2=ele 3=azi 4=aziele

__global__ __launch_bounds__(NTHR) void metric_fused(
    const float* __restrict__ doa_gt, const float* __restrict__ vad_gt,
    const float* __restrict__ doa_est, const float* __restrict__ vad_est,
    float* __restrict__ part, unsigned int* __restrict__ counter,
    float* __restrict__ out)
{
    const int gid = blockIdx.x * NTHR + threadIdx.x;

    float act = 0.f, corr = 0.f, s_ele = 0.f, s_azi = 0.f, s_ae = 0.f;

    const float4* dg = reinterpret_cast<const float4*>(doa_gt);
    const float4* de = reinterpret_cast<const float4*>(doa_est);
    const float4* vg_p = reinterpret_cast<const float4*>(vad_gt);
    const float4* ve_p = reinterpret_cast<const float4*>(vad_est);

#pragma unroll
    for (int p = 0; p < NPASS; ++p) {
        const int i = p * (NBLK * NTHR) + gid;   // coalesced per pass

        // doa layout per (b,t): [2][4] floats = 32 B: ele[0..3] then azi[0..3]
        float4 eg = dg[2 * i], ag = dg[2 * i + 1];
        float4 ee = de[2 * i], ae = de[2 * i + 1];
        float4 vg4 = vg_p[i];
        float4 ve4 = ve_p[i];

        float egA[4] = {eg.x, eg.y, eg.z, eg.w}, agA[4] = {ag.x, ag.y, ag.z, ag.w};
        float eeA[4] = {ee.x, ee.y, ee.z, ee.w}, aeA[4] = {ae.x, ae.y, ae.z, ae.w};
        float vgA[4] = {vg4.x, vg4.y, vg4.z, vg4.w}, veA[4] = {ve4.x, ve4.y, ve4.z, ve4.w};

#pragma unroll
        for (int s = 0; s < 4; ++s) {
            float vg = (vgA[s] > VAD_TH) ? 1.f : 0.f;
            float ve = (veA[s] > VAD_TH) ? vg : 0.f;

            // floor-mod(d,360) for d in [-180,540]; bit-identical to numpy's
            // fmod-then-adjust (Sterbenz for the subtract branch).
            float d = aeA[s] - agA[s] + 180.f;
            d = (d < 0.f) ? d + 360.f : d;
            d = (d >= 360.f) ? d - 360.f : d;
            float azi_err = fabsf(d - 180.f);

            float ele_err = fabsf(eeA[s] - egA[s]);

            float gr = egA[s] * D2R;
            float er = eeA[s] * D2R;
            float ar = agA[s] * D2R - aeA[s] * D2R;
            float aux = __cosf(gr) * __cosf(er) + __sinf(gr) * __sinf(er) * __cosf(ar);
            aux = fminf(fmaxf(aux, -CLIPV), CLIPV);
            float ae_err = acosf(aux) * R2D;     // acos >= 0

            act += vg;
            if (azi_err < AE_TH) corr += ve;
            s_ele += vg * ele_err;
            s_azi += vg * azi_err;
            s_ae  += vg * ae_err;
        }
    }

    // wave64 shuffle reduction
#pragma unroll
    for (int off = 32; off > 0; off >>= 1) {
        act   += __shfl_down(act,   off, 64);
        corr  += __shfl_down(corr,  off, 64);
        s_ele += __shfl_down(s_ele, off, 64);
        s_azi += __shfl_down(s_azi, off, 64);
        s_ae  += __shfl_down(s_ae,  off, 64);
    }

    __shared__ float sm[4][5];
    __shared__ int amLast;
    const int wave = threadIdx.x >> 6;
    const int lane = threadIdx.x & 63;
    if (lane == 0) {
        sm[wave][0] = act;  sm[wave][1] = corr; sm[wave][2] = s_ele;
        sm[wave][3] = s_azi; sm[wave][4] = s_ae;
    }
    __syncthreads();
    if (threadIdx.x == 0) {
        float a = sm[0][0] + sm[1][0] + sm[2][0] + sm[3][0];
        float c = sm[0][1] + sm[1][1] + sm[2][1] + sm[3][1];
        float e = sm[0][2] + sm[1][2] + sm[2][2] + sm[3][2];
        float z = sm[0][3] + sm[1][3] + sm[2][3] + sm[3][3];
        float x = sm[0][4] + sm[1][4] + sm[2][4] + sm[3][4];
        part[0 * NBLK + blockIdx.x] = a;
        part[1 * NBLK + blockIdx.x] = c;
        part[2 * NBLK + blockIdx.x] = e;
        part[3 * NBLK + blockIdx.x] = z;
        part[4 * NBLK + blockIdx.x] = x;
        __threadfence();                          // release: partials visible device-wide
        unsigned int prev = atomicAdd(counter, 1u);
        amLast = (prev == NBLK - 1) ? 1 : 0;
    }
    __syncthreads();
    if (!amLast) return;

    // ---- last block: finalize ----
    __threadfence();                              // acquire: invalidate stale cache
    const volatile float* vpart = part;
    const int t = threadIdx.x;
    double v[5];
#pragma unroll
    for (int m = 0; m < 5; ++m) {
        double acc = 0.0;
#pragma unroll
        for (int j = 0; j < NBLK / NTHR; ++j)
            acc += (double)vpart[m * NBLK + j * NTHR + t];
        v[m] = acc;
    }
#pragma unroll
    for (int off = 32; off > 0; off >>= 1)
#pragma unroll
        for (int m = 0; m < 5; ++m)
            v[m] += __shfl_down(v[m], off, 64);

    __shared__ double dsm[4][5];
    if (lane == 0)
#pragma unroll
        for (int m = 0; m < 5; ++m) dsm[wave][m] = v[m];
    __syncthreads();
    if (t == 0) {
        double tot[5];
#pragma unroll
        for (int m = 0; m < 5; ++m)
            tot[m] = dsm[0][m] + dsm[1][m] + dsm[2][m] + dsm[3][m];
        double act_t = tot[0];
        out[0] = (float)(tot[1] / act_t);   // ACC
        out[1] = (float)(tot[2] / act_t);   // MAE ele
        out[2] = (float)(tot[3] / act_t);   // MAE azi
        out[3] = (float)(tot[4] / act_t);   // MAE aziele
    }
}

} // namespace

extern "C" void kernel_launch(void* const* d_in, const int* in_sizes, int n_in,
                              void* d_out, int out_size, void* d_ws, size_t ws_size,
                              hipStream_t stream) {
    const float* doa_gt  = (const float*)d_in[0];
    const float* vad_gt  = (const float*)d_in[1];
    const float* doa_est = (const float*)d_in[2];
    const float* vad_est = (const float*)d_in[3];
    float* part = (float*)d_ws;                                  // 5*NBLK floats
    unsigned int* counter = (unsigned int*)((char*)d_ws + 5 * NBLK * sizeof(float));
    float* out  = (float*)d_out;

    hipMemsetAsync(counter, 0, sizeof(unsigned int), stream);    // ws is poisoned 0xAA
    metric_fused<<<NBLK, NTHR, 0, stream>>>(doa_gt, vad_gt, doa_est, vad_est,
                                            part, counter, out);
}

// Round 4
// 118.330 us; speedup vs baseline: 1.4379x; 1.4379x over previous
//
#include <hip/hip_runtime.h>
#include <math.h>

namespace {

constexpr int NB = 64, NT = 16384;
constexpr int NBT = NB * NT;              // 1,048,576 (b,t) pairs, 4 sources each
constexpr int NBLK   = 2048;              // blocks in main kernel
constexpr int NTHR   = 256;
constexpr int NPASS  = NBT / (NBLK * NTHR);   // 2 pairs per thread
constexpr float VAD_TH  = 2.0f / 3.0f;
constexpr float AE_TH   = 30.0f;
constexpr float D2R     = 0.017453292519943295f;
constexpr float R2D     = 57.29577951308232f;
constexpr float CLIPV   = 0.99999f;

// ws layout: float part[5][NBLK]  (SoA). metrics: 0=act 1=corr 2=ele 3=azi 4=aziele

__device__ __forceinline__ void process4(
    const float4& eg, const float4& ag, const float4& ee, const float4& ae,
    const float4& vg4, const float4& ve4,
    float& act, float& corr, float& s_ele, float& s_azi, float& s_ae)
{
    float egA[4] = {eg.x, eg.y, eg.z, eg.w}, agA[4] = {ag.x, ag.y, ag.z, ag.w};
    float eeA[4] = {ee.x, ee.y, ee.z, ee.w}, aeA[4] = {ae.x, ae.y, ae.z, ae.w};
    float vgA[4] = {vg4.x, vg4.y, vg4.z, vg4.w}, veA[4] = {ve4.x, ve4.y, ve4.z, ve4.w};

#pragma unroll
    for (int s = 0; s < 4; ++s) {
        float vg = (vgA[s] > VAD_TH) ? 1.f : 0.f;
        float ve = (veA[s] > VAD_TH) ? vg : 0.f;

        // floor-mod(d,360) for d in [-180,540]; bit-identical to numpy's
        // fmod-then-adjust (Sterbenz for the subtract branch).
        float d = aeA[s] - agA[s] + 180.f;
        d = (d < 0.f) ? d + 360.f : d;
        d = (d >= 360.f) ? d - 360.f : d;
        float azi_err = fabsf(d - 180.f);

        float ele_err = fabsf(eeA[s] - egA[s]);

        float gr = egA[s] * D2R;
        float er = eeA[s] * D2R;
        float ar = agA[s] * D2R - aeA[s] * D2R;
        float aux = __cosf(gr) * __cosf(er) + __sinf(gr) * __sinf(er) * __cosf(ar);
        aux = fminf(fmaxf(aux, -CLIPV), CLIPV);
        float ae_err = acosf(aux) * R2D;     // acos >= 0

        act += vg;
        if (azi_err < AE_TH) corr += ve;
        s_ele += vg * ele_err;
        s_azi += vg * azi_err;
        s_ae  += vg * ae_err;
    }
}

__global__ __launch_bounds__(NTHR) void metric_main(
    const float* __restrict__ doa_gt, const float* __restrict__ vad_gt,
    const float* __restrict__ doa_est, const float* __restrict__ vad_est,
    float* __restrict__ part)
{
    const int gid = blockIdx.x * NTHR + threadIdx.x;

    const float4* dg = reinterpret_cast<const float4*>(doa_gt);
    const float4* de = reinterpret_cast<const float4*>(doa_est);
    const float4* vg_p = reinterpret_cast<const float4*>(vad_gt);
    const float4* ve_p = reinterpret_cast<const float4*>(vad_est);

    // Issue ALL loads before any compute: 12 outstanding float4 loads/thread
    // (memory-level parallelism — round-3 evidence showed the loop is
    // latency-bound when passes serialize their loads).
    const int i0 = gid;                       // pass 0, coalesced
    const int i1 = gid + NBLK * NTHR;         // pass 1, coalesced
    static_assert(NPASS == 2, "load schedule assumes 2 passes");

    float4 eg0 = dg[2 * i0], ag0 = dg[2 * i0 + 1];
    float4 ee0 = de[2 * i0], ae0 = de[2 * i0 + 1];
    float4 eg1 = dg[2 * i1], ag1 = dg[2 * i1 + 1];
    float4 ee1 = de[2 * i1], ae1 = de[2 * i1 + 1];
    float4 vg40 = vg_p[i0], ve40 = ve_p[i0];
    float4 vg41 = vg_p[i1], ve41 = ve_p[i1];

    float act = 0.f, corr = 0.f, s_ele = 0.f, s_azi = 0.f, s_ae = 0.f;
    process4(eg0, ag0, ee0, ae0, vg40, ve40, act, corr, s_ele, s_azi, s_ae);
    process4(eg1, ag1, ee1, ae1, vg41, ve41, act, corr, s_ele, s_azi, s_ae);

    // wave64 shuffle reduction
#pragma unroll
    for (int off = 32; off > 0; off >>= 1) {
        act   += __shfl_down(act,   off, 64);
        corr  += __shfl_down(corr,  off, 64);
        s_ele += __shfl_down(s_ele, off, 64);
        s_azi += __shfl_down(s_azi, off, 64);
        s_ae  += __shfl_down(s_ae,  off, 64);
    }

    __shared__ float sm[4][5];
    const int wave = threadIdx.x >> 6;
    const int lane = threadIdx.x & 63;
    if (lane == 0) {
        sm[wave][0] = act;  sm[wave][1] = corr; sm[wave][2] = s_ele;
        sm[wave][3] = s_azi; sm[wave][4] = s_ae;
    }
    __syncthreads();
    if (threadIdx.x == 0) {
        part[0 * NBLK + blockIdx.x] = sm[0][0] + sm[1][0] + sm[2][0] + sm[3][0];
        part[1 * NBLK + blockIdx.x] = sm[0][1] + sm[1][1] + sm[2][1] + sm[3][1];
        part[2 * NBLK + blockIdx.x] = sm[0][2] + sm[1][2] + sm[2][2] + sm[3][2];
        part[3 * NBLK + blockIdx.x] = sm[0][3] + sm[1][3] + sm[2][3] + sm[3][3];
        part[4 * NBLK + blockIdx.x] = sm[0][4] + sm[1][4] + sm[2][4] + sm[3][4];
    }
}

// One block: reduce 5 x NBLK partials in double, write 4 outputs.
__global__ __launch_bounds__(NTHR) void metric_finalize(
    const float* __restrict__ part, float* __restrict__ out)
{
    __shared__ double dsm[4][5];
    const int t = threadIdx.x;
    double v[5];
#pragma unroll
    for (int m = 0; m < 5; ++m) {
        double acc = 0.0;
#pragma unroll
        for (int j = 0; j < NBLK / NTHR; ++j)
            acc += (double)part[m * NBLK + j * NTHR + t];
        v[m] = acc;
    }
#pragma unroll
    for (int off = 32; off > 0; off >>= 1)
#pragma unroll
        for (int m = 0; m < 5; ++m)
            v[m] += __shfl_down(v[m], off, 64);

    const int wave = t >> 6, lane = t & 63;
    if (lane == 0)
#pragma unroll
        for (int m = 0; m < 5; ++m) dsm[wave][m] = v[m];
    __syncthreads();
    if (t == 0) {
        double tot[5];
#pragma unroll
        for (int m = 0; m < 5; ++m)
            tot[m] = dsm[0][m] + dsm[1][m] + dsm[2][m] + dsm[3][m];
        double act = tot[0];
        out[0] = (float)(tot[1] / act);   // ACC
        out[1] = (float)(tot[2] / act);   // MAE ele
        out[2] = (float)(tot[3] / act);   // MAE azi
        out[3] = (float)(tot[4] / act);   // MAE aziele
    }
}

} // namespace

extern "C" void kernel_launch(void* const* d_in, const int* in_sizes, int n_in,
                              void* d_out, int out_size, void* d_ws, size_t ws_size,
                              hipStream_t stream) {
    const float* doa_gt  = (const float*)d_in[0];
    const float* vad_gt  = (const float*)d_in[1];
    const float* doa_est = (const float*)d_in[2];
    const float* vad_est = (const float*)d_in[3];
    float* part = (float*)d_ws;          // 5 * NBLK floats = 40 KB
    float* out  = (float*)d_out;

    metric_main<<<NBLK, NTHR, 0, stream>>>(doa_gt, vad_gt, doa_est, vad_est, part);
    metric_finalize<<<1, NTHR, 0, stream>>>(part, out);
}